// Round 3
// baseline (460.194 us; speedup 1.0000x reference)
//
#include <hip/hip_runtime.h>
#include <hip/hip_bf16.h>

#define T_SEQ 80
#define EMB   100
#define HU    128
#define G4    512
#define BR    16
#define THR3  512

typedef __attribute__((ext_vector_type(8))) short bfrag;
typedef __attribute__((ext_vector_type(4))) float f32x4;

// ws layout (bytes)
#define OFF_EW1P 0ull                       // 10000*512*2 = 10,240,000
#define OFF_U1T  10240000ull                // 131072
#define OFF_U2T  (OFF_U1T + 131072ull)
#define OFF_W2T  (OFF_U2T + 131072ull)      // pre-swizzled

__device__ inline unsigned short f2bf(float x) {
    __hip_bfloat16 h = __float2bfloat16(x);
    unsigned short u; __builtin_memcpy(&u, &h, 2); return u;
}
__device__ inline float bf2f(unsigned short u) {
    unsigned int v = ((unsigned int)u) << 16;
    float f; __builtin_memcpy(&f, &v, 4); return f;
}
__device__ inline float sigf(float x) {
    return __builtin_amdgcn_rcpf(1.f + __expf(-x));
}
__device__ inline float tanhf_(float x) {
    x = fminf(fmaxf(x, -15.f), 15.f);
    float e = __expf(-2.f * x);
    return (1.f - e) * __builtin_amdgcn_rcpf(1.f + e);
}
// A/B frag load from swizzled row-major [rows][128] bf16 LDS tile
__device__ inline bfrag ld_frag(const unsigned short* buf, int row, int kk, int lhi) {
    int byte = (row * 256 + kk * 64 + lhi * 16) ^ ((row & 7) << 4);
    return *(const bfrag*)((const char*)buf + byte);
}
__device__ inline void st_h(unsigned short* buf, int rr, int u, unsigned short v) {
    int byte = ((rr * 256 + u * 2) ^ ((rr & 7) << 4));
    *(unsigned short*)((char*)buf + byte) = v;
}

// ---- kernel 1: merged prep. blocks 0..624: vocab GEMM (EW1p = emb@W1+b1, bf16).
//      blocks 625..688: weight transpose U1T/U2T (linear) + W2T (XOR-swizzled).
#define VOCAB_BLKS 625
__global__ __launch_bounds__(512) void prep_all(
    const float* __restrict__ emb, const float* __restrict__ W1, const float* __restrict__ b1,
    const float* __restrict__ U1, const float* __restrict__ U2, const float* __restrict__ W2,
    unsigned short* __restrict__ EW1p, unsigned short* __restrict__ U1T,
    unsigned short* __restrict__ U2T, unsigned short* __restrict__ W2T) {
    const int tid = threadIdx.x;
    if (blockIdx.x < VOCAB_BLKS) {
        __shared__ float embs[16 * EMB];
        const int tok0 = blockIdx.x * 16;
        for (int i = tid; i < 16 * EMB; i += 512) embs[i] = emb[tok0 * EMB + i];
        __syncthreads();
        const int c = tid;               // z-column = g*128+u
        const int g = c >> 7, u = c & 127;
        float s[16];
        const float bias = b1[c];
#pragma unroll
        for (int tt = 0; tt < 16; tt++) s[tt] = bias;
        for (int e = 0; e < EMB; e++) {
            float wv = W1[e * G4 + c];
#pragma unroll
            for (int tt = 0; tt < 16; tt++) s[tt] += embs[tt * EMB + e] * wv;
        }
#pragma unroll
        for (int tt = 0; tt < 16; tt++)
            EW1p[(size_t)(tok0 + tt) * G4 + u * 4 + g] = f2bf(s[tt]);
    } else {
#pragma unroll
        for (int r = 0; r < 2; r++) {
            int idx = (blockIdx.x - VOCAB_BLKS) * 1024 + r * 512 + tid;  // 0..65535
            int n = idx >> 7, k = idx & 127;
            U1T[n * 128 + k] = f2bf(U1[k * 512 + n]);
            U2T[n * 128 + k] = f2bf(U2[k * 512 + n]);
            int byte = (n * 256 + k * 2) ^ ((n & 7) << 4);
            W2T[byte >> 1] = f2bf(W2[k * 512 + n]);
        }
    }
}

// ---- kernel 2: fused 2-layer LSTM, wave-specialized pipeline.
// waves 0-3 (A): layer1 at step s.  waves 4-7 (B): layer2 at step s-1.
__global__ __launch_bounds__(THR3, 2) void lstm_fused(
    const int* __restrict__ tokens, const unsigned short* __restrict__ EW1p,
    const unsigned short* __restrict__ U1T, const unsigned short* __restrict__ U2T,
    const unsigned short* __restrict__ W2T, const float* __restrict__ b2,
    const float* __restrict__ Wd, const float* __restrict__ bd, float* __restrict__ out) {

    __shared__ unsigned short w2lds[G4 * HU];      // 131072 B, swizzled
    __shared__ unsigned short h1b[2][BR * HU];     // h1[t] in buf t&1
    __shared__ unsigned short h2b[2][BR * HU];     // h2[t] in buf t&1
    __shared__ int toklds[BR * T_SEQ];

    const int tid = threadIdx.x;
    const int w   = tid >> 6;
    const int l   = tid & 63;
    const int llo = l & 15, lhi = l >> 4;
    const int wa  = w & 3;
    const bool isA = (w < 4);
    const int n0  = wa * 32 + llo;                 // tile-0 unit
    const int n1  = n0 + 16;                       // tile-1 unit
    const int r0  = blockIdx.x * BR;

    { // stage pre-swizzled W2T -> LDS
        const uint4* src = (const uint4*)W2T;
        uint4* dst = (uint4*)w2lds;
#pragma unroll
        for (int i = 0; i < 16; i++) dst[tid + i * THR3] = src[tid + i * THR3];
    }
    for (int i = tid; i < BR * T_SEQ; i += THR3) toklds[i] = tokens[r0 * T_SEQ + i];
    for (int i = tid; i < BR * HU; i += THR3) {
        h1b[0][i] = 0; h1b[1][i] = 0; h2b[0][i] = 0; h2b[1][i] = 0;
    }

    // recurrent weights in registers: A gets U1 slice, B gets U2 slice (overlaid)
    bfrag us[2][4][4];
    {
        const unsigned short* UT = isA ? U1T : U2T;
#pragma unroll
        for (int p = 0; p < 2; p++) {
            const int n = p ? n1 : n0;
#pragma unroll
            for (int g = 0; g < 4; g++)
#pragma unroll
                for (int kk = 0; kk < 4; kk++)
                    us[p][g][kk] = *(const bfrag*)(UT + (size_t)(g * 128 + n) * 128 + kk * 32 + lhi * 8);
        }
    }
    float bb[2][4];
#pragma unroll
    for (int p = 0; p < 2; p++)
#pragma unroll
        for (int g = 0; g < 4; g++) bb[p][g] = b2[g * 128 + (p ? n1 : n0)];

    float c_st[8] = {0, 0, 0, 0, 0, 0, 0, 0};
    f32x4 acc[2][4];

    __syncthreads();

    // prologue: A prefetches EW1p gathers for t=0
    ushort4 zv[2][4];
    if (isA) {
#pragma unroll
        for (int j = 0; j < 4; j++) {
            int tok = toklds[(lhi * 4 + j) * T_SEQ + 0];
            const unsigned short* base = EW1p + (size_t)tok * G4;
            zv[0][j] = *(const ushort4*)(base + n0 * 4);
            zv[1][j] = *(const ushort4*)(base + n1 * 4);
        }
    }

    for (int s = 0; s <= T_SEQ; ++s) {
        const unsigned short* h1prev = h1b[(s + 1) & 1];   // h1[s-1]
        if (isA) {
            if (s < T_SEQ) {
                // consume prefetched gathers: acc = x_t@W1 + b1
#pragma unroll
                for (int p = 0; p < 2; p++)
#pragma unroll
                    for (int j = 0; j < 4; j++) {
                        acc[p][0][j] = bf2f(zv[p][j].x);
                        acc[p][1][j] = bf2f(zv[p][j].y);
                        acc[p][2][j] = bf2f(zv[p][j].z);
                        acc[p][3][j] = bf2f(zv[p][j].w);
                    }
                // prefetch next step's gathers (zv regs now dead)
                const int tn = (s + 1 < T_SEQ) ? s + 1 : T_SEQ - 1;
#pragma unroll
                for (int j = 0; j < 4; j++) {
                    int tok = toklds[(lhi * 4 + j) * T_SEQ + tn];
                    const unsigned short* base = EW1p + (size_t)tok * G4;
                    zv[0][j] = *(const ushort4*)(base + n0 * 4);
                    zv[1][j] = *(const ushort4*)(base + n1 * 4);
                }
                // h1[s-1] @ U1
                bfrag a[4];
#pragma unroll
                for (int kk = 0; kk < 4; kk++) a[kk] = ld_frag(h1prev, llo, kk, lhi);
#pragma unroll
                for (int p = 0; p < 2; p++)
#pragma unroll
                    for (int g = 0; g < 4; g++)
#pragma unroll
                        for (int kk = 0; kk < 4; kk++)
                            acc[p][g] = __builtin_amdgcn_mfma_f32_16x16x32_bf16(a[kk], us[p][g][kk], acc[p][g], 0, 0, 0);
                unsigned short* h1nxt = h1b[s & 1];
#pragma unroll
                for (int p = 0; p < 2; p++) {
                    const int n = p ? n1 : n0;
#pragma unroll
                    for (int j = 0; j < 4; j++) {
                        float zi = acc[p][0][j], zf = acc[p][1][j];
                        float zg = acc[p][2][j], zo = acc[p][3][j];
                        float cn = sigf(zf) * c_st[p * 4 + j] + sigf(zi) * tanhf_(zg);
                        c_st[p * 4 + j] = cn;
                        st_h(h1nxt, lhi * 4 + j, n, f2bf(sigf(zo) * tanhf_(cn)));
                    }
                }
            }
        } else {
            if (s >= 1) {
                const unsigned short* h2prev = h2b[s & 1];  // h2[s-2]
                bfrag a1[4], a2[4];
#pragma unroll
                for (int kk = 0; kk < 4; kk++) a1[kk] = ld_frag(h1prev, llo, kk, lhi);
#pragma unroll
                for (int kk = 0; kk < 4; kk++) a2[kk] = ld_frag(h2prev, llo, kk, lhi);
#pragma unroll
                for (int p = 0; p < 2; p++) {
                    const int n = p ? n1 : n0;
#pragma unroll
                    for (int g = 0; g < 4; g++) {
                        acc[p][g] = (f32x4){bb[p][g], bb[p][g], bb[p][g], bb[p][g]};
#pragma unroll
                        for (int kk = 0; kk < 4; kk++) {
                            bfrag wf = ld_frag(w2lds, g * 128 + n, kk, lhi);
                            acc[p][g] = __builtin_amdgcn_mfma_f32_16x16x32_bf16(a1[kk], wf, acc[p][g], 0, 0, 0);
                        }
#pragma unroll
                        for (int kk = 0; kk < 4; kk++)
                            acc[p][g] = __builtin_amdgcn_mfma_f32_16x16x32_bf16(a2[kk], us[p][g][kk], acc[p][g], 0, 0, 0);
                    }
                }
                unsigned short* h2nxt = h2b[(s + 1) & 1];   // h2[s-1]
#pragma unroll
                for (int p = 0; p < 2; p++) {
                    const int n = p ? n1 : n0;
#pragma unroll
                    for (int j = 0; j < 4; j++) {
                        float zi = acc[p][0][j], zf = acc[p][1][j];
                        float zg = acc[p][2][j], zo = acc[p][3][j];
                        float cn = sigf(zf) * c_st[p * 4 + j] + sigf(zi) * tanhf_(zg);
                        c_st[p * 4 + j] = cn;
                        st_h(h2nxt, lhi * 4 + j, n, f2bf(sigf(zo) * tanhf_(cn)));
                    }
                }
            }
        }
        __syncthreads();
    }

    // ---- dense head: out = sigmoid(h2[79] @ Wd + bd); h2[79] is in h2b[1]
    if (w == 0) {
        int r = l >> 2, q = l & 3;
        float s = 0.f;
        for (int k = q * 32; k < q * 32 + 32; k++) {
            int byte = (r * 256 + k * 2) ^ ((r & 7) << 4);
            s += bf2f(*(const unsigned short*)((const char*)h2b[1] + byte)) * Wd[k];
        }
        s += __shfl_xor(s, 1, 64);
        s += __shfl_xor(s, 2, 64);
        if (q == 0) out[r0 + r] = sigf(s + bd[0]);
    }
}

extern "C" void kernel_launch(void* const* d_in, const int* in_sizes, int n_in,
                              void* d_out, int out_size, void* d_ws, size_t ws_size,
                              hipStream_t stream) {
    const int*   tokens = (const int*)  d_in[0];
    const float* emb    = (const float*)d_in[1];
    const float* W1     = (const float*)d_in[2];
    const float* U1     = (const float*)d_in[3];
    const float* b1     = (const float*)d_in[4];
    const float* W2     = (const float*)d_in[5];
    const float* U2     = (const float*)d_in[6];
    const float* b2     = (const float*)d_in[7];
    const float* Wd     = (const float*)d_in[8];
    const float* bd     = (const float*)d_in[9];
    float* out = (float*)d_out;

    char* ws = (char*)d_ws;
    unsigned short* EW1p = (unsigned short*)(ws + OFF_EW1P);
    unsigned short* U1T  = (unsigned short*)(ws + OFF_U1T);
    unsigned short* U2T  = (unsigned short*)(ws + OFF_U2T);
    unsigned short* W2T  = (unsigned short*)(ws + OFF_W2T);

    prep_all<<<VOCAB_BLKS + 64, 512, 0, stream>>>(emb, W1, b1, U1, U2, W2, EW1p, U1T, U2T, W2T);
    lstm_fused<<<256, THR3, 0, stream>>>(tokens, EW1p, U1T, U2T, W2T, b2, Wd, bd, out);
}

// Round 5
// 413.515 us; speedup vs baseline: 1.1129x; 1.1129x over previous
//
#include <hip/hip_runtime.h>
#include <hip/hip_bf16.h>

#define T_SEQ 80
#define EMB   100
#define HU    128
#define G4    512
#define BR    16
#define THR   512

typedef __attribute__((ext_vector_type(8))) short bfrag;
typedef __attribute__((ext_vector_type(4))) float f32x4;

// ws layout (bytes)
#define OFF_EW1P 0ull                       // 10000*512*2 = 10,240,000
#define OFF_U1T  10240000ull                // 131072
#define OFF_U2T  (OFF_U1T + 131072ull)
#define OFF_W2T  (OFF_U2T + 131072ull)

__device__ inline unsigned short f2bf(float x) {
    __hip_bfloat16 h = __float2bfloat16(x);
    unsigned short u; __builtin_memcpy(&u, &h, 2); return u;
}
__device__ inline float bf2f(unsigned short u) {
    unsigned int v = ((unsigned int)u) << 16;
    float f; __builtin_memcpy(&f, &v, 4); return f;
}
// exp2-native gates: v_exp_f32 computes 2^x. Saturate correctly at +/-inf args.
__device__ inline float sig2(float x) {
    return __builtin_amdgcn_rcpf(1.f + __builtin_amdgcn_exp2f(-1.44269504f * x));
}
__device__ inline float tanh2(float x) {
    return 1.f - 2.f * __builtin_amdgcn_rcpf(1.f + __builtin_amdgcn_exp2f(2.88539008f * x));
}
// A-frag load from swizzled row-major [16][128] bf16 LDS tile
__device__ inline bfrag ld_frag(const unsigned short* buf, int row, int kk, int lhi) {
    int byte = (row * 256 + kk * 64 + lhi * 16) ^ ((row & 7) << 4);
    return *(const bfrag*)((const char*)buf + byte);
}
__device__ inline void st_h(unsigned short* buf, int rr, int u, unsigned short v) {
    int byte = ((rr * 256 + u * 2) ^ ((rr & 7) << 4));
    *(unsigned short*)((char*)buf + byte) = v;
}

// ---- kernel 1: merged prep. blocks 0..624: vocab GEMM (EW1p = emb@W1+b1, bf16,
//      gate-interleaved layout [tok][u*4+g]). blocks 625..688: U1/U2/W2 -> bf16 [n][k].
#define VOCAB_BLKS 625
__global__ __launch_bounds__(512) void prep_all(
    const float* __restrict__ emb, const float* __restrict__ W1, const float* __restrict__ b1,
    const float* __restrict__ U1, const float* __restrict__ U2, const float* __restrict__ W2,
    unsigned short* __restrict__ EW1p, unsigned short* __restrict__ U1T,
    unsigned short* __restrict__ U2T, unsigned short* __restrict__ W2T) {
    const int tid = threadIdx.x;
    if (blockIdx.x < VOCAB_BLKS) {
        __shared__ float embs[16 * EMB];
        const int tok0 = blockIdx.x * 16;
        for (int i = tid; i < 16 * EMB; i += 512) embs[i] = emb[tok0 * EMB + i];
        __syncthreads();
        const int c = tid;               // z-column = g*128+u
        const int g = c >> 7, u = c & 127;
        float s[16];
        const float bias = b1[c];
#pragma unroll
        for (int tt = 0; tt < 16; tt++) s[tt] = bias;
        for (int e = 0; e < EMB; e++) {
            float wv = W1[e * G4 + c];
#pragma unroll
            for (int tt = 0; tt < 16; tt++) s[tt] += embs[tt * EMB + e] * wv;
        }
#pragma unroll
        for (int tt = 0; tt < 16; tt++)
            EW1p[(size_t)(tok0 + tt) * G4 + u * 4 + g] = f2bf(s[tt]);
    } else {
#pragma unroll
        for (int r = 0; r < 2; r++) {
            int idx = (blockIdx.x - VOCAB_BLKS) * 1024 + r * 512 + tid;  // 0..65535
            int n = idx >> 7, k = idx & 127;
            U1T[n * 128 + k] = f2bf(U1[k * 512 + n]);
            U2T[n * 128 + k] = f2bf(U2[k * 512 + n]);
            W2T[n * 128 + k] = f2bf(W2[k * 512 + n]);
        }
    }
}

// ---- kernel 2: fused 2-layer LSTM, lockstep waves, ALL weights in registers,
//      ONE barrier per step (phase = L2(s-1) ; L1(s), sharing h1(s-1) A-frags).
__global__ __launch_bounds__(THR, 2) void lstm_fused(
    const int* __restrict__ tokens, const unsigned short* __restrict__ EW1p,
    const unsigned short* __restrict__ U1T, const unsigned short* __restrict__ U2T,
    const unsigned short* __restrict__ W2T, const float* __restrict__ b2,
    const float* __restrict__ Wd, const float* __restrict__ bd, float* __restrict__ out) {

    __shared__ unsigned short h1b[2][BR * HU];     // h1[s] in buf s&1
    __shared__ unsigned short h2b[2][BR * HU];     // h2[s] in buf s&1
    __shared__ int toklds[BR * T_SEQ];

    const int tid = threadIdx.x;
    const int w   = tid >> 6;
    const int l   = tid & 63;
    const int llo = l & 15, lhi = l >> 4;
    const int u   = w * 16 + llo;                  // unit owned by this lane
    const int r0  = blockIdx.x * BR;

    for (int i = tid; i < BR * T_SEQ; i += THR) toklds[i] = tokens[r0 * T_SEQ + i];
    for (int i = tid; i < BR * HU; i += THR) {
        h1b[0][i] = 0; h1b[1][i] = 0; h2b[0][i] = 0; h2b[1][i] = 0;
    }

    // all three weight slices in registers: 48 frags = 192 VGPR
    bfrag u1r[4][4], u2r[4][4], w2r[4][4];
#pragma unroll
    for (int g = 0; g < 4; g++)
#pragma unroll
        for (int kk = 0; kk < 4; kk++) {
            size_t off = (size_t)(g * 128 + u) * 128 + kk * 32 + lhi * 8;
            u1r[g][kk] = *(const bfrag*)(U1T + off);
            u2r[g][kk] = *(const bfrag*)(U2T + off);
            w2r[g][kk] = *(const bfrag*)(W2T + off);
        }
    float bb[4];
#pragma unroll
    for (int g = 0; g < 4; g++) bb[g] = b2[g * 128 + u];

    float c1[4] = {0, 0, 0, 0}, c2[4] = {0, 0, 0, 0};
    __syncthreads();

    // ---- prologue: L1(0). h1(-1)=0 so z1 = gathers only; write h1(0)->h1b[0].
    ushort4 zv[4];
#pragma unroll
    for (int j = 0; j < 4; j++) {
        int tok = toklds[(lhi * 4 + j) * T_SEQ + 0];
        zv[j] = *(const ushort4*)(EW1p + (size_t)tok * G4 + u * 4);
    }
#pragma unroll
    for (int j = 0; j < 4; j++) {
        float zi = bf2f(zv[j].x), zf = bf2f(zv[j].y);
        float zg = bf2f(zv[j].z), zo = bf2f(zv[j].w);
        float cn = sig2(zf) * c1[j] + sig2(zi) * tanh2(zg);
        c1[j] = cn;
        st_h(h1b[0], lhi * 4 + j, u, f2bf(sig2(zo) * tanh2(cn)));
    }
    // prefetch gathers for s=1
#pragma unroll
    for (int j = 0; j < 4; j++) {
        int tok = toklds[(lhi * 4 + j) * T_SEQ + 1];
        zv[j] = *(const ushort4*)(EW1p + (size_t)tok * G4 + u * 4);
    }
    __syncthreads();

    // ---- main loop: phase s = { L2(s-1); L1(s) }, one barrier
#pragma unroll 2
    for (int s = 1; s < T_SEQ; ++s) {
        const unsigned short* h1prev = h1b[(s - 1) & 1];   // h1(s-1)
        const unsigned short* h2prev = h2b[s & 1];         // h2(s-2)
        unsigned short* h1nxt = h1b[s & 1];                // h1(s)
        unsigned short* h2nxt = h2b[(s - 1) & 1];          // h2(s-1)

        // consume prefetched gathers into acc1; then prefetch s+1
        f32x4 acc1[4], acc2[4];
#pragma unroll
        for (int j = 0; j < 4; j++) {
            acc1[0][j] = bf2f(zv[j].x);
            acc1[1][j] = bf2f(zv[j].y);
            acc1[2][j] = bf2f(zv[j].z);
            acc1[3][j] = bf2f(zv[j].w);
        }
        const int tn = (s + 1 < T_SEQ) ? s + 1 : s;
#pragma unroll
        for (int j = 0; j < 4; j++) {
            int tok = toklds[(lhi * 4 + j) * T_SEQ + tn];
            zv[j] = *(const ushort4*)(EW1p + (size_t)tok * G4 + u * 4);
        }
#pragma unroll
        for (int g = 0; g < 4; g++) acc2[g] = (f32x4){bb[g], bb[g], bb[g], bb[g]};

        // shared A-frags over h1(s-1): feed both W2 (acc2) and U1 (acc1)
#pragma unroll
        for (int kk = 0; kk < 4; kk++) {
            bfrag a = ld_frag(h1prev, llo, kk, lhi);
#pragma unroll
            for (int g = 0; g < 4; g++)
                acc2[g] = __builtin_amdgcn_mfma_f32_16x16x32_bf16(a, w2r[g][kk], acc2[g], 0, 0, 0);
#pragma unroll
            for (int g = 0; g < 4; g++)
                acc1[g] = __builtin_amdgcn_mfma_f32_16x16x32_bf16(a, u1r[g][kk], acc1[g], 0, 0, 0);
        }
#pragma unroll
        for (int kk = 0; kk < 4; kk++) {
            bfrag a = ld_frag(h2prev, llo, kk, lhi);
#pragma unroll
            for (int g = 0; g < 4; g++)
                acc2[g] = __builtin_amdgcn_mfma_f32_16x16x32_bf16(a, u2r[g][kk], acc2[g], 0, 0, 0);
        }

        // epilogue L2 -> h2(s-1)
#pragma unroll
        for (int j = 0; j < 4; j++) {
            float zi = acc2[0][j], zf = acc2[1][j], zg = acc2[2][j], zo = acc2[3][j];
            float cn = sig2(zf) * c2[j] + sig2(zi) * tanh2(zg);
            c2[j] = cn;
            st_h(h2nxt, lhi * 4 + j, u, f2bf(sig2(zo) * tanh2(cn)));
        }
        // epilogue L1 -> h1(s)
#pragma unroll
        for (int j = 0; j < 4; j++) {
            float zi = acc1[0][j], zf = acc1[1][j], zg = acc1[2][j], zo = acc1[3][j];
            float cn = sig2(zf) * c1[j] + sig2(zi) * tanh2(zg);
            c1[j] = cn;
            st_h(h1nxt, lhi * 4 + j, u, f2bf(sig2(zo) * tanh2(cn)));
        }
        __syncthreads();
    }

    // ---- tail: L2(79). reads h1(79)=h1b[1], h2(78)=h2b[0]; writes h2(79)->h2b[1]
    {
        const unsigned short* h1last = h1b[1];
        const unsigned short* h2prev = h2b[0];
        f32x4 acc2[4];
#pragma unroll
        for (int g = 0; g < 4; g++) acc2[g] = (f32x4){bb[g], bb[g], bb[g], bb[g]};
#pragma unroll
        for (int kk = 0; kk < 4; kk++) {
            bfrag a = ld_frag(h1last, llo, kk, lhi);
#pragma unroll
            for (int g = 0; g < 4; g++)
                acc2[g] = __builtin_amdgcn_mfma_f32_16x16x32_bf16(a, w2r[g][kk], acc2[g], 0, 0, 0);
        }
#pragma unroll
        for (int kk = 0; kk < 4; kk++) {
            bfrag a = ld_frag(h2prev, llo, kk, lhi);
#pragma unroll
            for (int g = 0; g < 4; g++)
                acc2[g] = __builtin_amdgcn_mfma_f32_16x16x32_bf16(a, u2r[g][kk], acc2[g], 0, 0, 0);
        }
#pragma unroll
        for (int j = 0; j < 4; j++) {
            float zi = acc2[0][j], zf = acc2[1][j], zg = acc2[2][j], zo = acc2[3][j];
            float cn = sig2(zf) * c2[j] + sig2(zi) * tanh2(zg);
            c2[j] = cn;
            st_h(h2b[1], lhi * 4 + j, u, f2bf(sig2(zo) * tanh2(cn)));
        }
    }
    __syncthreads();

    // ---- dense head: out = sigmoid(h2(79) @ Wd + bd); h2(79) in h2b[1]
    if (w == 0) {
        int r = l >> 2, q = l & 3;
        float s = 0.f;
        for (int k = q * 32; k < q * 32 + 32; k++) {
            int byte = (r * 256 + k * 2) ^ ((r & 7) << 4);
            s += bf2f(*(const unsigned short*)((const char*)h2b[1] + byte)) * Wd[k];
        }
        s += __shfl_xor(s, 1, 64);
        s += __shfl_xor(s, 2, 64);
        if (q == 0) out[r0 + r] = sig2(s + bd[0]);
    }
}

extern "C" void kernel_launch(void* const* d_in, const int* in_sizes, int n_in,
                              void* d_out, int out_size, void* d_ws, size_t ws_size,
                              hipStream_t stream) {
    const int*   tokens = (const int*)  d_in[0];
    const float* emb    = (const float*)d_in[1];
    const float* W1     = (const float*)d_in[2];
    const float* U1     = (const float*)d_in[3];
    const float* b1     = (const float*)d_in[4];
    const float* W2     = (const float*)d_in[5];
    const float* U2     = (const float*)d_in[6];
    const float* b2     = (const float*)d_in[7];
    const float* Wd     = (const float*)d_in[8];
    const float* bd     = (const float*)d_in[9];
    float* out = (float*)d_out;

    char* ws = (char*)d_ws;
    unsigned short* EW1p = (unsigned short*)(ws + OFF_EW1P);
    unsigned short* U1T  = (unsigned short*)(ws + OFF_U1T);
    unsigned short* U2T  = (unsigned short*)(ws + OFF_U2T);
    unsigned short* W2T  = (unsigned short*)(ws + OFF_W2T);

    prep_all<<<VOCAB_BLKS + 64, 512, 0, stream>>>(emb, W1, b1, U1, U2, W2, EW1p, U1T, U2T, W2T);
    lstm_fused<<<256, THR, 0, stream>>>(tokens, EW1p, U1T, U2T, W2T, b2, Wd, bd, out);
}

// Round 7
// 286.315 us; speedup vs baseline: 1.6073x; 1.4443x over previous
//
#include <hip/hip_runtime.h>
#include <hip/hip_bf16.h>

#define T_SEQ 80
#define EMB   100
#define HU    128
#define G4    512
#define BR    16
#define THR   512
#define LOG2E 1.44269504f

typedef __attribute__((ext_vector_type(8))) short bfrag;
typedef __attribute__((ext_vector_type(4))) float f32x4;

// ws layout (bytes)
#define OFF_EW1P 0ull                       // 10000*512*2 = 10,240,000
#define OFF_U1T  10240000ull                // 131072
#define OFF_U2T  (OFF_U1T + 131072ull)
#define OFF_W2T  (OFF_U2T + 131072ull)

__device__ inline unsigned short f2bf(float x) {
    __hip_bfloat16 h = __float2bfloat16(x);
    unsigned short u; __builtin_memcpy(&u, &h, 2); return u;
}
__device__ inline float bf2f(unsigned short u) {
    unsigned int v = ((unsigned int)u) << 16;
    float f; __builtin_memcpy(&f, &v, 4); return f;
}
// gates on PRE-SCALED z: i/f/o columns scaled by -log2e, g columns by +2log2e
__device__ inline float sig_p(float zp) {       // sigmoid(x), zp = -log2e*x
    return __builtin_amdgcn_rcpf(1.f + __builtin_amdgcn_exp2f(zp));
}
__device__ inline float tanh_p(float zp) {      // tanh(x), zp = 2log2e*x
    return 1.f - 2.f * __builtin_amdgcn_rcpf(1.f + __builtin_amdgcn_exp2f(zp));
}
__device__ inline float tanh_r(float x) {       // tanh on raw x (cell state)
    return 1.f - 2.f * __builtin_amdgcn_rcpf(1.f + __builtin_amdgcn_exp2f(2.f * LOG2E * x));
}
__device__ inline float sig_r(float x) {        // sigmoid on raw x (head)
    return __builtin_amdgcn_rcpf(1.f + __builtin_amdgcn_exp2f(-LOG2E * x));
}
// A/B frag load from swizzled row-major [rows][128] bf16 LDS tile
__device__ inline bfrag ld_frag(const unsigned short* buf, int row, int kk, int lhi) {
    int byte = (row * 256 + kk * 64 + lhi * 16) ^ ((row & 7) << 4);
    return *(const bfrag*)((const char*)buf + byte);
}
__device__ inline void st_h(unsigned short* buf, int rr, int u, unsigned short v) {
    int byte = ((rr * 256 + u * 2) ^ ((rr & 7) << 4));
    *(unsigned short*)((char*)buf + byte) = v;
}

// ---- kernel 1: merged prep, with gate pre-scaling baked into all z-producing
//      weights. blocks 0..399: vocab GEMM (EW1p = scale*(emb@W1+b1), bf16,
//      layout [tok][u*4+g]). blocks 400..463: U1/U2/W2 transpose+scale -> bf16 [n][k].
#define K2_TOKS 25
#define VOCAB_BLKS 400
__global__ __launch_bounds__(512) void prep_all(
    const float* __restrict__ emb, const float* __restrict__ W1, const float* __restrict__ b1,
    const float* __restrict__ U1, const float* __restrict__ U2, const float* __restrict__ W2,
    unsigned short* __restrict__ EW1p, unsigned short* __restrict__ U1T,
    unsigned short* __restrict__ U2T, unsigned short* __restrict__ W2T) {
    const int tid = threadIdx.x;
    if (blockIdx.x < VOCAB_BLKS) {
        __shared__ float embs[K2_TOKS * EMB];
        const int tok0 = blockIdx.x * K2_TOKS;
        for (int i = tid; i < K2_TOKS * EMB; i += 512) embs[i] = emb[tok0 * EMB + i];
        __syncthreads();
        const int c = tid;               // z-column = g*128+u
        const int g = c >> 7, u = c & 127;
        const float scale = (g == 2) ? 2.f * LOG2E : -LOG2E;
        float s[K2_TOKS];
        const float bias = b1[c];
#pragma unroll
        for (int tt = 0; tt < K2_TOKS; tt++) s[tt] = bias;
        for (int e = 0; e < EMB; e++) {
            float wv = W1[e * G4 + c];
#pragma unroll
            for (int tt = 0; tt < K2_TOKS; tt++) s[tt] += embs[tt * EMB + e] * wv;
        }
#pragma unroll
        for (int tt = 0; tt < K2_TOKS; tt++)
            EW1p[(size_t)(tok0 + tt) * G4 + u * 4 + g] = f2bf(s[tt] * scale);
    } else {
#pragma unroll
        for (int r = 0; r < 2; r++) {
            int idx = (blockIdx.x - VOCAB_BLKS) * 1024 + r * 512 + tid;  // 0..65535
            int n = idx >> 7, k = idx & 127;
            const float scale = ((n >> 7) == 2) ? 2.f * LOG2E : -LOG2E;
            U1T[n * 128 + k] = f2bf(U1[k * 512 + n] * scale);
            U2T[n * 128 + k] = f2bf(U2[k * 512 + n] * scale);
            W2T[n * 128 + k] = f2bf(W2[k * 512 + n] * scale);
        }
    }
}

// ---- kernel 2: fused 2-layer LSTM. 8 lockstep waves; U1,U2 in regs (AGPR),
//      W2 in LDS; ONE barrier per phase = { L1(s); L2(s-1) } sharing h1(s-1) A-frags.
__global__ __launch_bounds__(THR, 2) void lstm_fused(
    const int* __restrict__ tokens, const unsigned short* __restrict__ EW1p,
    const unsigned short* __restrict__ U1T, const unsigned short* __restrict__ U2T,
    const unsigned short* __restrict__ W2T, const float* __restrict__ b2,
    const float* __restrict__ Wd, const float* __restrict__ bd, float* __restrict__ out) {

    __shared__ unsigned short w2lds[G4 * HU];      // 131072 B, swizzled rows
    __shared__ unsigned short h1b[2][BR * HU];     // h1(s) in buf s&1
    __shared__ unsigned short h2b[2][BR * HU];     // h2(s) in buf s&1
    __shared__ int toklds[BR * T_SEQ];

    const int tid = threadIdx.x;
    const int w   = tid >> 6;
    const int l   = tid & 63;
    const int llo = l & 15, lhi = l >> 4;
    const int u   = w * 16 + llo;                  // unit owned by this lane
    const int r0  = blockIdx.x * BR;

    { // stage pre-transposed W2T -> LDS with row-XOR swizzle applied on store
      // (W2T is linear [n][k]; store each 16B chunk at its swizzled slot)
        for (int i = tid; i < G4 * HU / 8; i += THR) {   // 8 shorts per chunk
            int n = i >> 4, c16 = i & 15;                // row, 16B-chunk in row
            int byte = (n * 256 + c16 * 16) ^ ((n & 7) << 4);
            *(uint4*)((char*)w2lds + byte) = *(const uint4*)(W2T + n * 128 + c16 * 8);
        }
    }
    for (int i = tid; i < BR * T_SEQ; i += THR) toklds[i] = tokens[r0 * T_SEQ + i];
    for (int i = tid; i < BR * HU; i += THR) { h2b[0][i] = 0; h2b[1][i] = 0; }

    // recurrent weights in registers (AGPR-eligible: MFMA B operands only)
    bfrag u1r[4][4], u2r[4][4];
#pragma unroll
    for (int g = 0; g < 4; g++)
#pragma unroll
        for (int kk = 0; kk < 4; kk++) {
            size_t off = (size_t)(g * 128 + u) * 128 + kk * 32 + lhi * 8;
            u1r[g][kk] = *(const bfrag*)(U1T + off);
            u2r[g][kk] = *(const bfrag*)(U2T + off);
        }
    float bb[4];
#pragma unroll
    for (int g = 0; g < 4; g++) bb[g] = b2[g * 128 + u] * ((g == 2) ? 2.f * LOG2E : -LOG2E);

    float c1[4] = {0, 0, 0, 0}, c2[4] = {0, 0, 0, 0};
    ushort4 zv[4];

    __syncthreads();

    // ---- prologue: L1(0). h1(-1)=0 so z1 = gathers only; write h1(0)->h1b[0].
#pragma unroll
    for (int j = 0; j < 4; j++) {
        int tok = toklds[(lhi * 4 + j) * T_SEQ + 0];
        zv[j] = *(const ushort4*)(EW1p + (size_t)tok * G4 + u * 4);
    }
#pragma unroll
    for (int j = 0; j < 4; j++) {
        float si = sig_p(bf2f(zv[j].x)), sf = sig_p(bf2f(zv[j].y));
        float tg = tanh_p(bf2f(zv[j].z)), so = sig_p(bf2f(zv[j].w));
        float cn = sf * c1[j] + si * tg;
        c1[j] = cn;
        st_h(h1b[0], lhi * 4 + j, u, f2bf(so * tanh_r(cn)));
    }
    // prefetch gathers for s=1
#pragma unroll
    for (int j = 0; j < 4; j++) {
        int tok = toklds[(lhi * 4 + j) * T_SEQ + 1];
        zv[j] = *(const ushort4*)(EW1p + (size_t)tok * G4 + u * 4);
    }
    __syncthreads();

    // phase(sn, bufs): L1(s) then L2(s-1); sn = prefetch index (s+1 clamped)
    auto phase = [&](int sn, const unsigned short* h1p, const unsigned short* h2p,
                     unsigned short* h1n, unsigned short* h2n) {
        f32x4 acc1[4];
#pragma unroll
        for (int j = 0; j < 4; j++) {
            acc1[0][j] = bf2f(zv[j].x); acc1[1][j] = bf2f(zv[j].y);
            acc1[2][j] = bf2f(zv[j].z); acc1[3][j] = bf2f(zv[j].w);
        }
        bfrag a1[4];
#pragma unroll
        for (int kk = 0; kk < 4; kk++) a1[kk] = ld_frag(h1p, llo, kk, lhi);
        // prefetch next phase's gathers (hide L2/L3 latency under MFMA+epilogue)
#pragma unroll
        for (int j = 0; j < 4; j++) {
            int tok = toklds[(lhi * 4 + j) * T_SEQ + sn];
            zv[j] = *(const ushort4*)(EW1p + (size_t)tok * G4 + u * 4);
        }
        // L1: acc1 += h1(s-1) @ U1
#pragma unroll
        for (int g = 0; g < 4; g++)
#pragma unroll
            for (int kk = 0; kk < 4; kk++)
                acc1[g] = __builtin_amdgcn_mfma_f32_16x16x32_bf16(a1[kk], u1r[g][kk], acc1[g], 0, 0, 0);
#pragma unroll
        for (int j = 0; j < 4; j++) {
            float si = sig_p(acc1[0][j]), sf = sig_p(acc1[1][j]);
            float tg = tanh_p(acc1[2][j]), so = sig_p(acc1[3][j]);
            float cn = sf * c1[j] + si * tg;
            c1[j] = cn;
            st_h(h1n, lhi * 4 + j, u, f2bf(so * tanh_r(cn)));
        }
        // L2: acc2 = b2 + h1(s-1) @ W2 + h2(s-2) @ U2   (reuses a1 frags)
        f32x4 acc2[4];
#pragma unroll
        for (int g = 0; g < 4; g++) acc2[g] = (f32x4){bb[g], bb[g], bb[g], bb[g]};
#pragma unroll
        for (int g = 0; g < 4; g++)
#pragma unroll
            for (int kk = 0; kk < 4; kk++) {
                bfrag wf = ld_frag(w2lds, g * 128 + u, kk, lhi);
                acc2[g] = __builtin_amdgcn_mfma_f32_16x16x32_bf16(a1[kk], wf, acc2[g], 0, 0, 0);
            }
#pragma unroll
        for (int kk = 0; kk < 4; kk++) {
            bfrag a2 = ld_frag(h2p, llo, kk, lhi);
#pragma unroll
            for (int g = 0; g < 4; g++)
                acc2[g] = __builtin_amdgcn_mfma_f32_16x16x32_bf16(a2, u2r[g][kk], acc2[g], 0, 0, 0);
        }
#pragma unroll
        for (int j = 0; j < 4; j++) {
            float si = sig_p(acc2[0][j]), sf = sig_p(acc2[1][j]);
            float tg = tanh_p(acc2[2][j]), so = sig_p(acc2[3][j]);
            float cn = sf * c2[j] + si * tg;
            c2[j] = cn;
            st_h(h2n, lhi * 4 + j, u, f2bf(so * tanh_r(cn)));
        }
        __syncthreads();
    };

    // phases s=1..79; h1prev=h1b[(s-1)&1], h2prev=h2b[s&1], h1nxt=h1b[s&1], h2nxt=h2b[(s-1)&1]
    phase(2, h1b[0], h2b[1], h1b[1], h2b[0]);                       // s=1
#pragma unroll 1
    for (int s = 2; s < T_SEQ - 1; s += 2) {
        phase(s + 1, h1b[1], h2b[0], h1b[0], h2b[1]);               // even s
        phase((s + 2 < T_SEQ) ? s + 2 : T_SEQ - 1,
              h1b[0], h2b[1], h1b[1], h2b[0]);                      // odd s+1
    }

    // ---- tail: L2(79). reads h1(79)=h1b[1], h2(78)=h2b[0]; writes h2(79)->h2b[1]
    {
        f32x4 acc2[4];
#pragma unroll
        for (int g = 0; g < 4; g++) acc2[g] = (f32x4){bb[g], bb[g], bb[g], bb[g]};
#pragma unroll
        for (int kk = 0; kk < 4; kk++) {
            bfrag a1 = ld_frag(h1b[1], llo, kk, lhi);
#pragma unroll
            for (int g = 0; g < 4; g++) {
                bfrag wf = ld_frag(w2lds, g * 128 + u, kk, lhi);
                acc2[g] = __builtin_amdgcn_mfma_f32_16x16x32_bf16(a1, wf, acc2[g], 0, 0, 0);
            }
        }
#pragma unroll
        for (int kk = 0; kk < 4; kk++) {
            bfrag a2 = ld_frag(h2b[0], llo, kk, lhi);
#pragma unroll
            for (int g = 0; g < 4; g++)
                acc2[g] = __builtin_amdgcn_mfma_f32_16x16x32_bf16(a2, u2r[g][kk], acc2[g], 0, 0, 0);
        }
#pragma unroll
        for (int j = 0; j < 4; j++) {
            float si = sig_p(acc2[0][j]), sf = sig_p(acc2[1][j]);
            float tg = tanh_p(acc2[2][j]), so = sig_p(acc2[3][j]);
            float cn = sf * c2[j] + si * tg;
            c2[j] = cn;
            st_h(h2b[1], lhi * 4 + j, u, f2bf(so * tanh_r(cn)));
        }
    }
    __syncthreads();

    // ---- dense head: out = sigmoid(h2(79) @ Wd + bd); h2(79) in h2b[1]
    if (w == 0) {
        int r = l >> 2, q = l & 3;
        float s = 0.f;
        for (int k = q * 32; k < q * 32 + 32; k++) {
            int byte = (r * 256 + k * 2) ^ ((r & 7) << 4);
            s += bf2f(*(const unsigned short*)((const char*)h2b[1] + byte)) * Wd[k];
        }
        s += __shfl_xor(s, 1, 64);
        s += __shfl_xor(s, 2, 64);
        if (q == 0) out[r0 + r] = sig_r(s + bd[0]);
    }
}

extern "C" void kernel_launch(void* const* d_in, const int* in_sizes, int n_in,
                              void* d_out, int out_size, void* d_ws, size_t ws_size,
                              hipStream_t stream) {
    const int*   tokens = (const int*)  d_in[0];
    const float* emb    = (const float*)d_in[1];
    const float* W1     = (const float*)d_in[2];
    const float* U1     = (const float*)d_in[3];
    const float* b1     = (const float*)d_in[4];
    const float* W2     = (const float*)d_in[5];
    const float* U2     = (const float*)d_in[6];
    const float* b2     = (const float*)d_in[7];
    const float* Wd     = (const float*)d_in[8];
    const float* bd     = (const float*)d_in[9];
    float* out = (float*)d_out;

    char* ws = (char*)d_ws;
    unsigned short* EW1p = (unsigned short*)(ws + OFF_EW1P);
    unsigned short* U1T  = (unsigned short*)(ws + OFF_U1T);
    unsigned short* U2T  = (unsigned short*)(ws + OFF_U2T);
    unsigned short* W2T  = (unsigned short*)(ws + OFF_W2T);

    prep_all<<<VOCAB_BLKS + 64, 512, 0, stream>>>(emb, W1, b1, U1, U2, W2, EW1p, U1T, U2T, W2T);
    lstm_fused<<<256, THR, 0, stream>>>(tokens, EW1p, U1T, U2T, W2T, b2, Wd, bd, out);
}

// Round 8
// 267.337 us; speedup vs baseline: 1.7214x; 1.0710x over previous
//
#include <hip/hip_runtime.h>
#include <hip/hip_bf16.h>

#define T_SEQ 80
#define EMB   100
#define HU    128
#define G4    512
#define BR    16
#define THR   512
#define LOG2E 1.44269504f

typedef __attribute__((ext_vector_type(8))) short bfrag;
typedef __attribute__((ext_vector_type(4))) float f32x4;

// ws layout (bytes)
#define OFF_EW1P 0ull                       // 10000*512*2 = 10,240,000
#define OFF_U1T  10240000ull                // 131072
#define OFF_U2T  (OFF_U1T + 131072ull)
#define OFF_W2T  (OFF_U2T + 131072ull)

__device__ inline unsigned short f2bf(float x) {
    __hip_bfloat16 h = __float2bfloat16(x);
    unsigned short u; __builtin_memcpy(&u, &h, 2); return u;
}
__device__ inline float bf2f(unsigned short u) {
    unsigned int v = ((unsigned int)u) << 16;
    float f; __builtin_memcpy(&f, &v, 4); return f;
}
// gates on PRE-SCALED z: i/f/o columns scaled by -log2e, g columns by +2log2e
__device__ inline float sig_p(float zp) {       // sigmoid(x), zp = -log2e*x
    return __builtin_amdgcn_rcpf(1.f + __builtin_amdgcn_exp2f(zp));
}
__device__ inline float tanh_p(float zp) {      // tanh(x), zp = 2log2e*x
    return 1.f - 2.f * __builtin_amdgcn_rcpf(1.f + __builtin_amdgcn_exp2f(zp));
}
__device__ inline float tanh_r(float x) {       // tanh on raw x (cell state)
    return 1.f - 2.f * __builtin_amdgcn_rcpf(1.f + __builtin_amdgcn_exp2f(2.f * LOG2E * x));
}
__device__ inline float sig_r(float x) {        // sigmoid on raw x (head)
    return __builtin_amdgcn_rcpf(1.f + __builtin_amdgcn_exp2f(-LOG2E * x));
}
// A/B frag load from swizzled row-major [rows][128] bf16 LDS tile
__device__ inline bfrag ld_frag(const unsigned short* buf, int row, int kk, int lhi) {
    int byte = (row * 256 + kk * 64 + lhi * 16) ^ ((row & 7) << 4);
    return *(const bfrag*)((const char*)buf + byte);
}
__device__ inline void st_h(unsigned short* buf, int rr, int u, unsigned short v) {
    int byte = ((rr * 256 + u * 2) ^ ((rr & 7) << 4));
    *(unsigned short*)((char*)buf + byte) = v;
}
// barrier that drains ONLY LDS ops: global zv prefetch stays in flight across it.
// (lane-private global loads have no cross-wave hazard; LDS h-buf handoff needs lgkmcnt.)
__device__ inline void barrier_lgkm() {
    asm volatile("s_waitcnt lgkmcnt(0)\n\ts_barrier" ::: "memory");
}

// ---- kernel 1: merged prep, gate pre-scaling baked into all z-producing weights.
//      blocks 0..1249: vocab GEMM (EW1p = scale*(emb@W1+b1), bf16, [tok][u*4+g]).
//      blocks 1250..1313: U1/U2/W2 transpose+scale -> bf16 [n][k].
#define K2_TOKS 8
#define VOCAB_BLKS 1250
__global__ __launch_bounds__(512) void prep_all(
    const float* __restrict__ emb, const float* __restrict__ W1, const float* __restrict__ b1,
    const float* __restrict__ U1, const float* __restrict__ U2, const float* __restrict__ W2,
    unsigned short* __restrict__ EW1p, unsigned short* __restrict__ U1T,
    unsigned short* __restrict__ U2T, unsigned short* __restrict__ W2T) {
    const int tid = threadIdx.x;
    if (blockIdx.x < VOCAB_BLKS) {
        __shared__ float embs[K2_TOKS * EMB];
        const int tok0 = blockIdx.x * K2_TOKS;
        for (int i = tid; i < K2_TOKS * EMB; i += 512) embs[i] = emb[tok0 * EMB + i];
        __syncthreads();
        const int c = tid;               // z-column = g*128+u
        const int g = c >> 7, u = c & 127;
        const float scale = (g == 2) ? 2.f * LOG2E : -LOG2E;
        float s[K2_TOKS];
        const float bias = b1[c];
#pragma unroll
        for (int tt = 0; tt < K2_TOKS; tt++) s[tt] = bias;
        for (int e = 0; e < EMB; e++) {
            float wv = W1[e * G4 + c];
#pragma unroll
            for (int tt = 0; tt < K2_TOKS; tt++) s[tt] += embs[tt * EMB + e] * wv;
        }
#pragma unroll
        for (int tt = 0; tt < K2_TOKS; tt++)
            EW1p[(size_t)(tok0 + tt) * G4 + u * 4 + g] = f2bf(s[tt] * scale);
    } else {
#pragma unroll
        for (int r = 0; r < 2; r++) {
            int idx = (blockIdx.x - VOCAB_BLKS) * 1024 + r * 512 + tid;  // 0..65535
            int n = idx >> 7, k = idx & 127;
            const float scale = ((n >> 7) == 2) ? 2.f * LOG2E : -LOG2E;
            U1T[n * 128 + k] = f2bf(U1[k * 512 + n] * scale);
            U2T[n * 128 + k] = f2bf(U2[k * 512 + n] * scale);
            W2T[n * 128 + k] = f2bf(W2[k * 512 + n] * scale);
        }
    }
}

// ---- kernel 2: fused 2-layer LSTM. 8 lockstep waves; U1,U2 in regs (AGPR),
//      W2 in LDS; one lgkm-only barrier per phase = { L1(s); L2(s-1) }.
//      Phase body ordered for LDS/VALU/MFMA overlap.
__global__ __launch_bounds__(THR, 2) void lstm_fused(
    const int* __restrict__ tokens, const unsigned short* __restrict__ EW1p,
    const unsigned short* __restrict__ U1T, const unsigned short* __restrict__ U2T,
    const unsigned short* __restrict__ W2T, const float* __restrict__ b2,
    const float* __restrict__ Wd, const float* __restrict__ bd, float* __restrict__ out) {

    __shared__ unsigned short w2lds[G4 * HU];      // 131072 B, swizzled rows
    __shared__ unsigned short h1b[2][BR * HU];     // h1(s) in buf s&1
    __shared__ unsigned short h2b[2][BR * HU];     // h2(s) in buf s&1
    __shared__ int toklds[BR * T_SEQ];

    const int tid = threadIdx.x;
    const int w   = tid >> 6;
    const int l   = tid & 63;
    const int llo = l & 15, lhi = l >> 4;
    const int u   = w * 16 + llo;                  // unit owned by this lane
    const int r0  = blockIdx.x * BR;

    { // stage pre-transposed W2T -> LDS with row-XOR swizzle applied on store
        for (int i = tid; i < G4 * HU / 8; i += THR) {   // 8 shorts per chunk
            int n = i >> 4, c16 = i & 15;                // row, 16B-chunk in row
            int byte = (n * 256 + c16 * 16) ^ ((n & 7) << 4);
            *(uint4*)((char*)w2lds + byte) = *(const uint4*)(W2T + n * 128 + c16 * 8);
        }
    }
    for (int i = tid; i < BR * T_SEQ; i += THR) toklds[i] = tokens[r0 * T_SEQ + i];
    for (int i = tid; i < BR * HU; i += THR) { h2b[0][i] = 0; h2b[1][i] = 0; }

    // recurrent weights in registers (AGPR-eligible: MFMA B operands only)
    bfrag u1r[4][4], u2r[4][4];
#pragma unroll
    for (int g = 0; g < 4; g++)
#pragma unroll
        for (int kk = 0; kk < 4; kk++) {
            size_t off = (size_t)(g * 128 + u) * 128 + kk * 32 + lhi * 8;
            u1r[g][kk] = *(const bfrag*)(U1T + off);
            u2r[g][kk] = *(const bfrag*)(U2T + off);
        }
    float bb[4];
#pragma unroll
    for (int g = 0; g < 4; g++) bb[g] = b2[g * 128 + u] * ((g == 2) ? 2.f * LOG2E : -LOG2E);

    float c1[4] = {0, 0, 0, 0}, c2[4] = {0, 0, 0, 0};
    ushort4 zv[4];

    __syncthreads();

    // ---- prologue: L1(0). h1(-1)=0 so z1 = gathers only; write h1(0)->h1b[0].
#pragma unroll
    for (int j = 0; j < 4; j++) {
        int tok = toklds[(lhi * 4 + j) * T_SEQ + 0];
        zv[j] = *(const ushort4*)(EW1p + (size_t)tok * G4 + u * 4);
    }
#pragma unroll
    for (int j = 0; j < 4; j++) {
        float si = sig_p(bf2f(zv[j].x)), sf = sig_p(bf2f(zv[j].y));
        float tg = tanh_p(bf2f(zv[j].z)), so = sig_p(bf2f(zv[j].w));
        float cn = sf * c1[j] + si * tg;
        c1[j] = cn;
        st_h(h1b[0], lhi * 4 + j, u, f2bf(so * tanh_r(cn)));
    }
    // prefetch gathers for s=1
#pragma unroll
    for (int j = 0; j < 4; j++) {
        int tok = toklds[(lhi * 4 + j) * T_SEQ + 1];
        zv[j] = *(const ushort4*)(EW1p + (size_t)tok * G4 + u * 4);
    }
    __syncthreads();

    // phase(sn, bufs): step s = { L1(s); L2(s-1) }; sn = next prefetch step
    auto phase = [&](int sn, const unsigned short* h1p, const unsigned short* h2p,
                     unsigned short* h1n, unsigned short* h2n) {
        // (1) issue all A-frag LDS reads up front
        bfrag a1[4], a2[4];
#pragma unroll
        for (int kk = 0; kk < 4; kk++) a1[kk] = ld_frag(h1p, llo, kk, lhi);
#pragma unroll
        for (int kk = 0; kk < 4; kk++) a2[kk] = ld_frag(h2p, llo, kk, lhi);
        // (2) acc1 init from zv (VALU overlaps LDS latency)
        f32x4 acc1[4];
#pragma unroll
        for (int j = 0; j < 4; j++) {
            acc1[0][j] = bf2f(zv[j].x); acc1[1][j] = bf2f(zv[j].y);
            acc1[2][j] = bf2f(zv[j].z); acc1[3][j] = bf2f(zv[j].w);
        }
        // (3) prefetch next step's gathers (span the lgkm-only barrier)
#pragma unroll
        for (int j = 0; j < 4; j++) {
            int tok = toklds[(lhi * 4 + j) * T_SEQ + sn];
            zv[j] = *(const ushort4*)(EW1p + (size_t)tok * G4 + u * 4);
        }
        // (4) L1 MFMA: acc1 += h1(s-1) @ U1   (waits only on a1)
#pragma unroll
        for (int g = 0; g < 4; g++)
#pragma unroll
            for (int kk = 0; kk < 4; kk++)
                acc1[g] = __builtin_amdgcn_mfma_f32_16x16x32_bf16(a1[kk], u1r[g][kk], acc1[g], 0, 0, 0);
        // (5) acc2 init + U2 MFMA (waits on a2; W2 reads not yet issued)
        f32x4 acc2[4];
#pragma unroll
        for (int g = 0; g < 4; g++) acc2[g] = (f32x4){bb[g], bb[g], bb[g], bb[g]};
#pragma unroll
        for (int kk = 0; kk < 4; kk++)
#pragma unroll
            for (int g = 0; g < 4; g++)
                acc2[g] = __builtin_amdgcn_mfma_f32_16x16x32_bf16(a2[kk], u2r[g][kk], acc2[g], 0, 0, 0);
        // (6) issue W2 g=0 frags, then L1 epilogue (wf latency hides under VALU)
        bfrag wfc[4];
#pragma unroll
        for (int kk = 0; kk < 4; kk++) wfc[kk] = ld_frag(w2lds, 0 * 128 + u, kk, lhi);
#pragma unroll
        for (int j = 0; j < 4; j++) {
            float si = sig_p(acc1[0][j]), sf = sig_p(acc1[1][j]);
            float tg = tanh_p(acc1[2][j]), so = sig_p(acc1[3][j]);
            float cn = sf * c1[j] + si * tg;
            c1[j] = cn;
            st_h(h1n, lhi * 4 + j, u, f2bf(so * tanh_r(cn)));
        }
        // (7) W2 MFMAs, double-buffered frag loads (a1 reused as A operand)
#pragma unroll
        for (int g = 0; g < 4; g++) {
            bfrag wfn[4];
            if (g < 3) {
#pragma unroll
                for (int kk = 0; kk < 4; kk++) wfn[kk] = ld_frag(w2lds, (g + 1) * 128 + u, kk, lhi);
            }
#pragma unroll
            for (int kk = 0; kk < 4; kk++)
                acc2[g] = __builtin_amdgcn_mfma_f32_16x16x32_bf16(a1[kk], wfc[kk], acc2[g], 0, 0, 0);
            if (g < 3) {
#pragma unroll
                for (int kk = 0; kk < 4; kk++) wfc[kk] = wfn[kk];
            }
        }
        // (8) L2 epilogue -> h2n
#pragma unroll
        for (int j = 0; j < 4; j++) {
            float si = sig_p(acc2[0][j]), sf = sig_p(acc2[1][j]);
            float tg = tanh_p(acc2[2][j]), so = sig_p(acc2[3][j]);
            float cn = sf * c2[j] + si * tg;
            c2[j] = cn;
            st_h(h2n, lhi * 4 + j, u, f2bf(so * tanh_r(cn)));
        }
        barrier_lgkm();
    };

    // phases s=1..79
    phase(2, h1b[0], h2b[1], h1b[1], h2b[0]);                       // s=1
#pragma unroll 1
    for (int s = 2; s < T_SEQ - 1; s += 2) {
        phase(s + 1, h1b[1], h2b[0], h1b[0], h2b[1]);               // even s
        phase((s + 2 < T_SEQ) ? s + 2 : T_SEQ - 1,
              h1b[0], h2b[1], h1b[1], h2b[0]);                      // odd s+1
    }

    // ---- tail: L2(79). reads h1(79)=h1b[1], h2(78)=h2b[0]; writes h2(79)->h2b[1]
    {
        f32x4 acc2[4];
#pragma unroll
        for (int g = 0; g < 4; g++) acc2[g] = (f32x4){bb[g], bb[g], bb[g], bb[g]};
#pragma unroll
        for (int kk = 0; kk < 4; kk++) {
            bfrag a1 = ld_frag(h1b[1], llo, kk, lhi);
#pragma unroll
            for (int g = 0; g < 4; g++) {
                bfrag wf = ld_frag(w2lds, g * 128 + u, kk, lhi);
                acc2[g] = __builtin_amdgcn_mfma_f32_16x16x32_bf16(a1, wf, acc2[g], 0, 0, 0);
            }
        }
#pragma unroll
        for (int kk = 0; kk < 4; kk++) {
            bfrag a2 = ld_frag(h2b[0], llo, kk, lhi);
#pragma unroll
            for (int g = 0; g < 4; g++)
                acc2[g] = __builtin_amdgcn_mfma_f32_16x16x32_bf16(a2, u2r[g][kk], acc2[g], 0, 0, 0);
        }
#pragma unroll
        for (int j = 0; j < 4; j++) {
            float si = sig_p(acc2[0][j]), sf = sig_p(acc2[1][j]);
            float tg = tanh_p(acc2[2][j]), so = sig_p(acc2[3][j]);
            float cn = sf * c2[j] + si * tg;
            c2[j] = cn;
            st_h(h2b[1], lhi * 4 + j, u, f2bf(so * tanh_r(cn)));
        }
    }
    __syncthreads();

    // ---- dense head: out = sigmoid(h2(79) @ Wd + bd); h2(79) in h2b[1]
    if (w == 0) {
        int r = l >> 2, q = l & 3;
        float s = 0.f;
        for (int k = q * 32; k < q * 32 + 32; k++) {
            int byte = (r * 256 + k * 2) ^ ((r & 7) << 4);
            s += bf2f(*(const unsigned short*)((const char*)h2b[1] + byte)) * Wd[k];
        }
        s += __shfl_xor(s, 1, 64);
        s += __shfl_xor(s, 2, 64);
        if (q == 0) out[r0 + r] = sig_r(s + bd[0]);
    }
}

extern "C" void kernel_launch(void* const* d_in, const int* in_sizes, int n_in,
                              void* d_out, int out_size, void* d_ws, size_t ws_size,
                              hipStream_t stream) {
    const int*   tokens = (const int*)  d_in[0];
    const float* emb    = (const float*)d_in[1];
    const float* W1     = (const float*)d_in[2];
    const float* U1     = (const float*)d_in[3];
    const float* b1     = (const float*)d_in[4];
    const float* W2     = (const float*)d_in[5];
    const float* U2     = (const float*)d_in[6];
    const float* b2     = (const float*)d_in[7];
    const float* Wd     = (const float*)d_in[8];
    const float* bd     = (const float*)d_in[9];
    float* out = (float*)d_out;

    char* ws = (char*)d_ws;
    unsigned short* EW1p = (unsigned short*)(ws + OFF_EW1P);
    unsigned short* U1T  = (unsigned short*)(ws + OFF_U1T);
    unsigned short* U2T  = (unsigned short*)(ws + OFF_U2T);
    unsigned short* W2T  = (unsigned short*)(ws + OFF_W2T);

    prep_all<<<VOCAB_BLKS + 64, 512, 0, stream>>>(emb, W1, b1, U1, U2, W2, EW1p, U1T, U2T, W2T);
    lstm_fused<<<256, THR, 0, stream>>>(tokens, EW1p, U1T, U2T, W2T, b2, Wd, bd, out);
}